// Round 5
// baseline (1371.948 us; speedup 1.0000x reference)
//
#include <hip/hip_runtime.h>
#include <hip/hip_bf16.h>

// FlashFFN: y = nan_to_num(gelu_tanh(x@W1 + b1) @ W2) + b2
// Round 7: verified-template read choreography on the proven 4-slot ring.
// r6 falsified HBM-supply (FETCH -20%, dur flat). r5's cross-phase counted
// lgkm was NOT the verified m201 discipline. This round matches it exactly:
// per phase: [ds_read fragments (pre-barrier) | stage 2 gloads] -> barrier ->
// lgkmcnt(0) -> sched_barrier(0) -> setprio(1) -> 16 MFMA -> setprio(0) ->
// barrier. Overlap mechanism: barrier-arrival skew + per-wave lgkm(0) release
// staggered by LDS service order => one wave MFMAs while LDS feeds the next.
// B-fragments read once per K32 (phase A) and held in registers through
// phase B (no dbuf). vmcnt(8/4/0) tile-residency gate kept pre-barrier.
// Band mapping (r6) kept: FETCH reduction is free.

using bf16 = __hip_bfloat16;
typedef __attribute__((ext_vector_type(4))) float floatx4;
typedef __attribute__((ext_vector_type(8))) short shortx8;

#define TOKENS 4096   // B*S = 2*2048
#define DMODEL 4096
#define DFF    16384

__device__ __forceinline__ void gload_lds16(const void* g, void* l) {
  __builtin_amdgcn_global_load_lds(
      (const __attribute__((address_space(1))) unsigned int*)g,
      (__attribute__((address_space(3))) unsigned int*)l,
      16, 0, 0);
}

__device__ __forceinline__ unsigned lds_u32(const void* p) {
  return (unsigned)(unsigned long long)(const __attribute__((address_space(3))) char*)p;
}

__device__ __forceinline__ float gelu_tanh(float x) {
  // JAX default gelu (approximate=True, tanh form)
  float z = 0.7978845608028654f * (x + 0.044715f * x * x * x);
  float e = __expf(2.0f * z);   // inf -> t=1, 0 -> t=-1: both limits correct
  float t = 1.0f - 2.0f / (e + 1.0f);
  return 0.5f * x * (1.0f + t);
}

// ---- pre-pass: f32 -> bf16 cast (layout preserved), 8 elems/thread ----
__global__ void cvt_f32_bf16(const float* __restrict__ in, bf16* __restrict__ out) {
  int i = (blockIdx.x * blockDim.x + threadIdx.x) * 8;
  float4 a = *(const float4*)(in + i);
  float4 b = *(const float4*)(in + i + 4);
  union { shortx8 v; bf16 h[8]; } r;
  r.h[0] = __float2bfloat16(a.x); r.h[1] = __float2bfloat16(a.y);
  r.h[2] = __float2bfloat16(a.z); r.h[3] = __float2bfloat16(a.w);
  r.h[4] = __float2bfloat16(b.x); r.h[5] = __float2bfloat16(b.y);
  r.h[6] = __float2bfloat16(b.z); r.h[7] = __float2bfloat16(b.w);
  *(shortx8*)(out + i) = r.v;
}

// ---- pre-pass: transpose + cast. in [R][C] f32 -> out [C][R] bf16 ----
__global__ void transpose_cvt(const float* __restrict__ in, bf16* __restrict__ out,
                              int R, int C) {
  __shared__ float tile[64][65];
  const int c0 = blockIdx.x * 64, r0 = blockIdx.y * 64;
  const int t = threadIdx.x;
#pragma unroll
  for (int p = 0; p < 4; ++p) {
    int r = p * 16 + (t >> 4);
    int c = (t & 15) * 4;
    float4 v = *(const float4*)(in + (size_t)(r0 + r) * C + c0 + c);
    tile[r][c] = v.x; tile[r][c + 1] = v.y;
    tile[r][c + 2] = v.z; tile[r][c + 3] = v.w;
  }
  __syncthreads();
#pragma unroll
  for (int p = 0; p < 2; ++p) {
    int c = p * 32 + (t >> 3);
    int rb = (t & 7) * 8;
    union { shortx8 v; bf16 h[8]; } u;
#pragma unroll
    for (int j = 0; j < 8; ++j) u.h[j] = __float2bfloat16(tile[rb + j][c]);
    *(shortx8*)(out + (size_t)(c0 + c) * R + r0 + rb) = u.v;
  }
}

// ---- deep-pipelined GEMM: C = A @ Bt^T ----
// A [M][K] bf16 row-major, Bt [N][K] bf16 row-major. 256x256 tile, BK=32,
// 8 waves (2Mx4N), wave = 128x64 output via 8x4 16x16x32 MFMAs per K-tile.
// LDS ring: 4 slots x (256x32 A + 256x32 B). Staging swizzle (proven r2-r6):
// lane L covers row L>>2, src 16B-block (L&3)^((L>>3)&3); LDS linear.
//
// Per-K32-tile schedule (verified-template choreography):
//  Pa: ds_read A mi0-3 + B ni0-3 (8) | stage A(t+3) | BAR | lgkm(0) | SGB |
//      prio1 16xMFMA prio0 | BAR
//  Pb: ds_read A mi4-7 (4)          | stage B(t+3) | vmcnt gate | BAR |
//      lgkm(0) | SGB | prio1 16xMFMA prio0 | BAR
// Hazard ledger: slot (t+3)&3 == slot (t-1)&3; its last reads drained at
// Pb(t-1)'s lgkm(0), >=2 barriers before the overwriting gloads issue.
// vmcnt(8) pre-BAR guarantees tile t+1 resident globally one barrier before
// Pa(t+1)'s reads (8 = loads of tiles t+2,t+3 allowed in flight).
#define TILE_BODY(T)                                                            \
  {                                                                             \
    const int t_ = (T);                                                         \
    const unsigned aslot = As0 + (unsigned)(t_ & 3) * 16384u + a_foff;          \
    const unsigned bslot = Bs0 + (unsigned)(t_ & 3) * 16384u + b_foff;          \
    shortx8 ar0, ar1, ar2, ar3, br0, br1, br2, br3, cr0, cr1, cr2, cr3;         \
    /* ---------------- phase A ---------------- */                             \
    asm volatile("ds_read_b128 %0, %1 offset:0"    : "=v"(ar0) : "v"(aslot));   \
    asm volatile("ds_read_b128 %0, %1 offset:1024" : "=v"(ar1) : "v"(aslot));   \
    asm volatile("ds_read_b128 %0, %1 offset:2048" : "=v"(ar2) : "v"(aslot));   \
    asm volatile("ds_read_b128 %0, %1 offset:3072" : "=v"(ar3) : "v"(aslot));   \
    asm volatile("ds_read_b128 %0, %1 offset:0"    : "=v"(br0) : "v"(bslot));   \
    asm volatile("ds_read_b128 %0, %1 offset:1024" : "=v"(br1) : "v"(bslot));   \
    asm volatile("ds_read_b128 %0, %1 offset:2048" : "=v"(br2) : "v"(bslot));   \
    asm volatile("ds_read_b128 %0, %1 offset:3072" : "=v"(br3) : "v"(bslot));   \
    if (t_ + 3 < NT) {                       /* stage A(t+3) */                 \
      bf16* al = alw + ((t_ + 3) & 3) * 8192;                                   \
      const bf16* ag = agp + (size_t)(t_ + 3) * 32;                             \
      gload_lds16(ag, al);                                                      \
      gload_lds16(ag + 16 * Ks, al + 512);                                      \
    }                                                                           \
    __builtin_amdgcn_s_barrier();                                               \
    asm volatile("s_waitcnt lgkmcnt(0)");                                       \
    __builtin_amdgcn_sched_barrier(0);                                          \
    __builtin_amdgcn_s_setprio(1);                                              \
    {                                                                           \
      const shortx8 A_[4] = {ar0, ar1, ar2, ar3};                               \
      const shortx8 B_[4] = {br0, br1, br2, br3};                               \
      _Pragma("unroll")                                                         \
      for (int mi = 0; mi < 4; ++mi)                                            \
        _Pragma("unroll")                                                       \
        for (int ni = 0; ni < 4; ++ni)                                          \
          acc[mi][ni] = __builtin_amdgcn_mfma_f32_16x16x32_bf16(                \
              A_[mi], B_[ni], acc[mi][ni], 0, 0, 0);                            \
    }                                                                           \
    __builtin_amdgcn_s_setprio(0);                                              \
    __builtin_amdgcn_sched_barrier(0);                                          \
    __builtin_amdgcn_s_barrier();                                               \
    /* ---------------- phase B ---------------- */                             \
    asm volatile("ds_read_b128 %0, %1 offset:4096" : "=v"(cr0) : "v"(aslot));   \
    asm volatile("ds_read_b128 %0, %1 offset:5120" : "=v"(cr1) : "v"(aslot));   \
    asm volatile("ds_read_b128 %0, %1 offset:6144" : "=v"(cr2) : "v"(aslot));   \
    asm volatile("ds_read_b128 %0, %1 offset:7168" : "=v"(cr3) : "v"(aslot));   \
    if (t_ + 3 < NT) {                       /* stage B(t+3) */                 \
      bf16* bl = blw + ((t_ + 3) & 3) * 8192;                                   \
      const bf16* bg = bgp + (size_t)(t_ + 3) * 32;                             \
      gload_lds16(bg, bl);                                                      \
      gload_lds16(bg + 16 * Ks, bl + 512);                                      \
    }                                                                           \
    if (t_ + 3 < NT)      asm volatile("s_waitcnt vmcnt(8)");                   \
    else if (t_ + 2 < NT) asm volatile("s_waitcnt vmcnt(4)");                   \
    else if (t_ + 1 < NT) asm volatile("s_waitcnt vmcnt(0)");                   \
    __builtin_amdgcn_s_barrier();                                               \
    asm volatile("s_waitcnt lgkmcnt(0)");                                       \
    __builtin_amdgcn_sched_barrier(0);                                          \
    __builtin_amdgcn_s_setprio(1);                                              \
    {                                                                           \
      const shortx8 A_[4] = {cr0, cr1, cr2, cr3};                               \
      const shortx8 B_[4] = {br0, br1, br2, br3};                               \
      _Pragma("unroll")                                                         \
      for (int mi = 0; mi < 4; ++mi)                                            \
        _Pragma("unroll")                                                       \
        for (int ni = 0; ni < 4; ++ni)                                          \
          acc[4 + mi][ni] = __builtin_amdgcn_mfma_f32_16x16x32_bf16(            \
              A_[mi], B_[ni], acc[4 + mi][ni], 0, 0, 0);                        \
    }                                                                           \
    __builtin_amdgcn_s_setprio(0);                                              \
    __builtin_amdgcn_sched_barrier(0);                                          \
    __builtin_amdgcn_s_barrier();                                               \
  }

template <int FUSE_GELU>
__launch_bounds__(512, 2)
__global__ void gemm_bt(const bf16* __restrict__ A, const bf16* __restrict__ Bt,
                        const float* __restrict__ bias, void* __restrict__ Cout,
                        int M, int N, int K) {
  __shared__ __align__(16) bf16 As[4 * 256 * 32];   // 64 KiB
  __shared__ __align__(16) bf16 Bs[4 * 256 * 32];   // 64 KiB

  const int tid = threadIdx.x;
  const int wave = tid >> 6;
  const int lane = tid & 63;

  // LLC-aware band mapping (r6). M/256 == 16 for both GEMMs. Band = 256
  // blocks (16 m-rows x 16 n-tiles); XCD k (wg%8 round-robin) owns m-row-pair
  // {2k, 2k+1}. Bijective.
  const int wg8  = blockIdx.x & 255;
  const int xcd  = wg8 & 7;
  const int slot = wg8 >> 3;
  const int m0 = (2 * xcd + (slot & 1)) * 256;
  const int n0 = ((blockIdx.x >> 8) * 16 + (slot >> 1)) * 256;

  const size_t Ks = (size_t)K;
  const int NT = K >> 5;   // # of BK=32 K-tiles (128 or 512 here)

  const int srow = lane >> 2;
  const int kbsw = (lane & 3) ^ ((lane >> 3) & 3);
  const bf16* agp = A  + (size_t)(m0 + wave * 32 + srow) * Ks + kbsw * 8;
  const bf16* bgp = Bt + (size_t)(n0 + wave * 32 + srow) * Ks + kbsw * 8;
  bf16* const alw = As + wave * 1024;   // 32 rows * 32 cols
  bf16* const blw = Bs + wave * 1024;

  // fragment-read constants (16x16x32 MFMA)
  const int wr = wave >> 2, wc = wave & 3;
  const int wm = wr * 128, wn = wc * 64;
  const int fr = lane & 15;            // row within 16-row fragment
  const int q  = lane >> 4;            // which 8-elem k-block (0..3)
  const int sf = (fr >> 1) & 3;        // matches staging swizzle s(row)
  const int fk = (q ^ sf) * 8;

  const unsigned As0 = lds_u32(As);
  const unsigned Bs0 = lds_u32(Bs);
  const unsigned a_foff = (unsigned)((wm + fr) * 32 + fk) * 2;
  const unsigned b_foff = (unsigned)((wn + fr) * 32 + fk) * 2;

  floatx4 acc[8][4] = {};

  // prologue: stage K-tiles 0..2 into ring slots 0..2 (12 loads/thread)
#pragma unroll
  for (int pt = 0; pt < 3; ++pt) {
    bf16* al = alw + pt * 8192;
    bf16* bl = blw + pt * 8192;
    const bf16* ag = agp + (size_t)pt * 32;
    const bf16* bg = bgp + (size_t)pt * 32;
    gload_lds16(ag, al);
    gload_lds16(ag + 16 * Ks, al + 512);
    gload_lds16(bg, bl);
    gload_lds16(bg + 16 * Ks, bl + 512);
  }
  asm volatile("s_waitcnt vmcnt(8)");   // tile 0 resident (own loads)
  __builtin_amdgcn_s_barrier();         // tile 0 resident globally

  for (int t = 0; t < NT; ++t) {
    TILE_BODY(t)
  }

  // epilogue. C/D layout (m89/m91): col = lane&15, row = (lane>>4)*4 + reg
  const int col0 = n0 + wn + fr;
  const int row0 = m0 + wm + (lane >> 4) * 4;
#pragma unroll
  for (int ni = 0; ni < 4; ++ni) {
    const int col = col0 + ni * 16;
    const float bv = bias[col];
#pragma unroll
    for (int mi = 0; mi < 8; ++mi) {
#pragma unroll
      for (int r = 0; r < 4; ++r) {
        const int row = row0 + mi * 16 + r;
        float v = acc[mi][ni][r];
        if (FUSE_GELU) {
          v = gelu_tanh(v + bv);
          ((bf16*)Cout)[(size_t)row * N + col] = __float2bfloat16(v);
        } else {
          if (!isfinite(v)) v = 0.0f;   // nan_to_num BEFORE +b2
          ((float*)Cout)[(size_t)row * N + col] = v + bv;
        }
      }
    }
  }
}

extern "C" void kernel_launch(void* const* d_in, const int* in_sizes, int n_in,
                              void* d_out, int out_size, void* d_ws, size_t ws_size,
                              hipStream_t stream) {
  const float* x  = (const float*)d_in[0];
  const float* W1 = (const float*)d_in[1];
  const float* b1 = (const float*)d_in[2];
  const float* W2 = (const float*)d_in[3];
  const float* b2 = (const float*)d_in[4];
  float* out = (float*)d_out;

  // workspace layout (bf16): xb 32MB @0, h 128MB @32MB, w1t 128MB @160MB,
  // w2t 128MB @288MB (total 416 MB)
  char* ws = (char*)d_ws;
  bf16* xb  = (bf16*)(ws);
  bf16* h   = (bf16*)(ws + (size_t)32  * 1024 * 1024);
  bf16* w1t = (bf16*)(ws + (size_t)160 * 1024 * 1024);
  bf16* w2t = (bf16*)(ws + (size_t)288 * 1024 * 1024);

  cvt_f32_bf16<<<(TOKENS * DMODEL / 8) / 256, 256, 0, stream>>>(x, xb);
  transpose_cvt<<<dim3(DFF / 64, DMODEL / 64), 256, 0, stream>>>(W1, w1t, DMODEL, DFF);
  transpose_cvt<<<dim3(DMODEL / 64, DFF / 64), 256, 0, stream>>>(W2, w2t, DFF, DMODEL);

  // GEMM1: h = gelu(x @ W1 + b1)   [4096 x 16384] bf16
  gemm_bt<1><<<dim3((DFF / 256) * (TOKENS / 256)), 512, 0, stream>>>(
      xb, w1t, b1, h, TOKENS, DFF, DMODEL);

  // GEMM2: out = nan_guard(h @ W2) + b2   [4096 x 4096] f32
  gemm_bt<0><<<dim3((DMODEL / 256) * (TOKENS / 256)), 512, 0, stream>>>(
      h, w2t, b2, out, TOKENS, DMODEL, DFF);
}

// Round 7
// 1102.962 us; speedup vs baseline: 1.2439x; 1.2439x over previous
//
#include <hip/hip_runtime.h>
#include <hip/hip_bf16.h>

// FlashFFN: y = nan_to_num(gelu_tanh(x@W1 + b1) @ W2) + b2
// Round 9: round 8 (BK=64 data path) with the B-fragment ni-stride bug fixed.
// r8's epilogue maps acc[*][ni] -> col wc*16 + ni*64, but B ds_reads used
// ni-stride 4096 B (32 rows) instead of 8192 B (64 rows): acc[*][1] got B
// col +32, acc[*][3] got +160 -> absmax 5.04. Fix: B0 offsets {0,8192},
// B1 offsets {16384,24576}. Pipeline, swizzle, staging identical to r8
// (hazard ledger re-verified by vmcnt queue simulation).

using bf16 = __hip_bfloat16;
typedef __attribute__((ext_vector_type(4))) float floatx4;
typedef __attribute__((ext_vector_type(8))) short shortx8;

#define TOKENS 4096   // B*S = 2*2048
#define DMODEL 4096
#define DFF    16384

__device__ __forceinline__ void gload_lds16(const void* g, void* l) {
  __builtin_amdgcn_global_load_lds(
      (const __attribute__((address_space(1))) unsigned int*)g,
      (__attribute__((address_space(3))) unsigned int*)l,
      16, 0, 0);
}

__device__ __forceinline__ unsigned lds_u32(const void* p) {
  return (unsigned)(unsigned long long)(const __attribute__((address_space(3))) char*)p;
}

__device__ __forceinline__ float gelu_tanh(float x) {
  // JAX default gelu (approximate=True, tanh form)
  float z = 0.7978845608028654f * (x + 0.044715f * x * x * x);
  float e = __expf(2.0f * z);   // inf -> t=1, 0 -> t=-1: both limits correct
  float t = 1.0f - 2.0f / (e + 1.0f);
  return 0.5f * x * (1.0f + t);
}

#define DSR(dst, addr, off) \
  asm volatile("ds_read_b128 %0, %1 offset:" #off : "=v"(dst) : "v"(addr))

// ---- pre-pass: f32 -> bf16 cast (layout preserved), 8 elems/thread ----
__global__ void cvt_f32_bf16(const float* __restrict__ in, bf16* __restrict__ out) {
  int i = (blockIdx.x * blockDim.x + threadIdx.x) * 8;
  float4 a = *(const float4*)(in + i);
  float4 b = *(const float4*)(in + i + 4);
  union { shortx8 v; bf16 h[8]; } r;
  r.h[0] = __float2bfloat16(a.x); r.h[1] = __float2bfloat16(a.y);
  r.h[2] = __float2bfloat16(a.z); r.h[3] = __float2bfloat16(a.w);
  r.h[4] = __float2bfloat16(b.x); r.h[5] = __float2bfloat16(b.y);
  r.h[6] = __float2bfloat16(b.z); r.h[7] = __float2bfloat16(b.w);
  *(shortx8*)(out + i) = r.v;
}

// ---- pre-pass: transpose + cast. in [R][C] f32 -> out [C][R] bf16 ----
__global__ void transpose_cvt(const float* __restrict__ in, bf16* __restrict__ out,
                              int R, int C) {
  __shared__ float tile[64][65];
  const int c0 = blockIdx.x * 64, r0 = blockIdx.y * 64;
  const int t = threadIdx.x;
#pragma unroll
  for (int p = 0; p < 4; ++p) {
    int r = p * 16 + (t >> 4);
    int c = (t & 15) * 4;
    float4 v = *(const float4*)(in + (size_t)(r0 + r) * C + c0 + c);
    tile[r][c] = v.x; tile[r][c + 1] = v.y;
    tile[r][c + 2] = v.z; tile[r][c + 3] = v.w;
  }
  __syncthreads();
#pragma unroll
  for (int p = 0; p < 2; ++p) {
    int c = p * 32 + (t >> 3);
    int rb = (t & 7) * 8;
    union { shortx8 v; bf16 h[8]; } u;
#pragma unroll
    for (int j = 0; j < 8; ++j) u.h[j] = __float2bfloat16(tile[rb + j][c]);
    *(shortx8*)(out + (size_t)(c0 + c) * R + r0 + rb) = u.v;
  }
}

// ---- BK=64 deep-pipelined GEMM: C = A @ Bt^T ----
template <int FUSE_GELU>
__launch_bounds__(512, 2)
__global__ void gemm_bt(const bf16* __restrict__ A, const bf16* __restrict__ Bt,
                        const float* __restrict__ bias, void* __restrict__ Cout,
                        int M, int N, int K) {
  // [dbuf][half][128][64] bf16 each
  __shared__ __align__(16) bf16 As[2 * 2 * 128 * 64];   // 64 KiB
  __shared__ __align__(16) bf16 Bs[2 * 2 * 128 * 64];   // 64 KiB

  const int tid = threadIdx.x;
  const int wave = tid >> 6;
  const int lane = tid & 63;

  // LLC-aware band mapping (r6, kept): nwg % 256 == 0 for both GEMMs.
  const int wg8  = blockIdx.x & 255;
  const int xcd  = wg8 & 7;
  const int slot = wg8 >> 3;
  const int m0 = (2 * xcd + (slot & 1)) * 256;
  const int n0 = ((blockIdx.x >> 8) * 16 + (slot >> 1)) * 256;

  const size_t Ks = (size_t)K;
  const int NT = K >> 6;   // # of BK=64 K-tiles (64 or 256 here)

  // ---- staging addressing: wave-instr = 8 contiguous rows x 128 B ----
  // lane l covers (row w*8+(l>>3), stored 16B-blk l&7); source blk is the
  // inverse swizzle (l&7)^((l>>3)&7). Per (half,j): + (h*128+j*64) rows.
  const int swz = (lane & 7) ^ ((lane >> 3) & 7);
  const bf16* agp = A  + (size_t)(m0 + wave * 8 + (lane >> 3)) * Ks + swz * 8;
  const bf16* bgp = Bt + (size_t)(n0 + wave * 8 + (lane >> 3)) * Ks + swz * 8;

  // ---- fragment-read addressing (16x16x32 MFMA, strided wave tiling) ----
  const int wr = wave >> 2, wc = wave & 3;   // 2M x 4N
  const int fr = lane & 15;                  // row within 16x16 frag
  const int q  = lane >> 4;                  // 8-elem k-subblock (0..3)
  const unsigned As0 = lds_u32(As);
  const unsigned Bs0 = lds_u32(Bs);
  // stored blk = (kk*4+q) ^ (fr&7): bit2 = kk^((fr>>2)&1), bits01 = q^(fr&3)
  const unsigned aK0 = As0 + (unsigned)((wr * 16 + fr) * 128 +
                       (((fr >> 2) & 1) * 64) + ((q ^ (fr & 3)) * 16));
  const unsigned aK1 = aK0 ^ 64u;
  const unsigned bK0 = Bs0 + (unsigned)((wc * 16 + fr) * 128 +
                       (((fr >> 2) & 1) * 64) + ((q ^ (fr & 3)) * 16));
  const unsigned bK1 = bK0 ^ 64u;

  floatx4 acc[8][4] = {};

  // ---- prologue: stage tile 0 in queue order A0,B0,A1,B1 ----
  {
    bf16* lA = As + wave * 512;
    bf16* lB = Bs + wave * 512;
    gload_lds16(agp,             lA);
    gload_lds16(agp +  64 * Ks,  lA + 4096);
    gload_lds16(bgp,             lB);
    gload_lds16(bgp +  64 * Ks,  lB + 4096);
    gload_lds16(agp + 128 * Ks,  lA + 8192);
    gload_lds16(agp + 192 * Ks,  lA + 12288);
    gload_lds16(bgp + 128 * Ks,  lB + 8192);
    gload_lds16(bgp + 192 * Ks,  lB + 12288);
  }
  asm volatile("s_waitcnt vmcnt(4)");   // A-h0, B-h0 resident
  __builtin_amdgcn_s_barrier();

  for (int t = 0; t < NT; ++t) {
    const unsigned dsel = (unsigned)(t & 1) << 15;
    const unsigned a0 = aK0 + dsel, a1 = aK1 + dsel;
    const unsigned b0 = bK0 + dsel, b1 = bK1 + dsel;
    const bool st = (t + 1 < NT);
    const bf16* gA = agp + (size_t)(t + 1) * 64;
    const bf16* gB = bgp + (size_t)(t + 1) * 64;
    bf16* lA = As + ((t + 1) & 1) * 16384 + wave * 512;
    bf16* lB = Bs + ((t + 1) & 1) * 16384 + wave * 512;

    shortx8 A0[2][4], A1[2][4], B0[2][2], B1[2][2];

    // ============ phase 1: read A-h0(8) + B-h0(4); stage A-h0(t+1) ========
    DSR(A0[0][0], a0, 0);     DSR(A0[0][1], a0, 4096);
    DSR(A0[0][2], a0, 8192);  DSR(A0[0][3], a0, 12288);
    DSR(A0[1][0], a1, 0);     DSR(A0[1][1], a1, 4096);
    DSR(A0[1][2], a1, 8192);  DSR(A0[1][3], a1, 12288);
    DSR(B0[0][0], b0, 0);     DSR(B0[0][1], b0, 8192);
    DSR(B0[1][0], b1, 0);     DSR(B0[1][1], b1, 8192);
    if (st) { gload_lds16(gA, lA); gload_lds16(gA + 64 * Ks, lA + 4096); }
    __builtin_amdgcn_s_barrier();
    asm volatile("s_waitcnt lgkmcnt(0)");
    __builtin_amdgcn_sched_barrier(0);
    __builtin_amdgcn_s_setprio(1);
#pragma unroll
    for (int f = 0; f < 4; ++f)
#pragma unroll
      for (int n = 0; n < 2; ++n) {
        acc[f][n] = __builtin_amdgcn_mfma_f32_16x16x32_bf16(A0[0][f], B0[0][n], acc[f][n], 0, 0, 0);
        acc[f][n] = __builtin_amdgcn_mfma_f32_16x16x32_bf16(A0[1][f], B0[1][n], acc[f][n], 0, 0, 0);
      }
    __builtin_amdgcn_s_setprio(0);
    __builtin_amdgcn_sched_barrier(0);
    if (st) asm volatile("s_waitcnt vmcnt(4)");   // t.A1 done
    else    asm volatile("s_waitcnt vmcnt(2)");
    __builtin_amdgcn_s_barrier();

    // ============ phase 2: read A-h1(8); stage B-h0(t+1) ===================
    DSR(A1[0][0], a0, 16384); DSR(A1[0][1], a0, 20480);
    DSR(A1[0][2], a0, 24576); DSR(A1[0][3], a0, 28672);
    DSR(A1[1][0], a1, 16384); DSR(A1[1][1], a1, 20480);
    DSR(A1[1][2], a1, 24576); DSR(A1[1][3], a1, 28672);
    if (st) { gload_lds16(gB, lB); gload_lds16(gB + 64 * Ks, lB + 4096); }
    __builtin_amdgcn_s_barrier();
    asm volatile("s_waitcnt lgkmcnt(0)");
    __builtin_amdgcn_sched_barrier(0);
    __builtin_amdgcn_s_setprio(1);
#pragma unroll
    for (int f = 0; f < 4; ++f)
#pragma unroll
      for (int n = 0; n < 2; ++n) {
        acc[4 + f][n] = __builtin_amdgcn_mfma_f32_16x16x32_bf16(A1[0][f], B0[0][n], acc[4 + f][n], 0, 0, 0);
        acc[4 + f][n] = __builtin_amdgcn_mfma_f32_16x16x32_bf16(A1[1][f], B0[1][n], acc[4 + f][n], 0, 0, 0);
      }
    __builtin_amdgcn_s_setprio(0);
    __builtin_amdgcn_sched_barrier(0);
    if (st) asm volatile("s_waitcnt vmcnt(4)");   // t.B1 done
    else    asm volatile("s_waitcnt vmcnt(0)");
    __builtin_amdgcn_s_barrier();

    // ============ phase 3: read B-h1(4); stage A-h1(t+1) ===================
    DSR(B1[0][0], b0, 16384); DSR(B1[0][1], b0, 24576);
    DSR(B1[1][0], b1, 16384); DSR(B1[1][1], b1, 24576);
    if (st) { gload_lds16(gA + 128 * Ks, lA + 8192); gload_lds16(gA + 192 * Ks, lA + 12288); }
    __builtin_amdgcn_s_barrier();
    asm volatile("s_waitcnt lgkmcnt(0)");
    __builtin_amdgcn_sched_barrier(0);
    __builtin_amdgcn_s_setprio(1);
#pragma unroll
    for (int f = 0; f < 4; ++f)
#pragma unroll
      for (int n = 0; n < 2; ++n) {
        acc[f][2 + n] = __builtin_amdgcn_mfma_f32_16x16x32_bf16(A0[0][f], B1[0][n], acc[f][2 + n], 0, 0, 0);
        acc[f][2 + n] = __builtin_amdgcn_mfma_f32_16x16x32_bf16(A0[1][f], B1[1][n], acc[f][2 + n], 0, 0, 0);
      }
    __builtin_amdgcn_s_setprio(0);
    __builtin_amdgcn_sched_barrier(0);
    __builtin_amdgcn_s_barrier();

    // ============ phase 4: no reads; stage B-h1(t+1) =======================
    if (st) { gload_lds16(gB + 128 * Ks, lB + 8192); gload_lds16(gB + 192 * Ks, lB + 12288); }
    __builtin_amdgcn_s_setprio(1);
#pragma unroll
    for (int f = 0; f < 4; ++f)
#pragma unroll
      for (int n = 0; n < 2; ++n) {
        acc[4 + f][2 + n] = __builtin_amdgcn_mfma_f32_16x16x32_bf16(A1[0][f], B1[0][n], acc[4 + f][2 + n], 0, 0, 0);
        acc[4 + f][2 + n] = __builtin_amdgcn_mfma_f32_16x16x32_bf16(A1[1][f], B1[1][n], acc[4 + f][2 + n], 0, 0, 0);
      }
    __builtin_amdgcn_s_setprio(0);
    __builtin_amdgcn_sched_barrier(0);
    if (st) asm volatile("s_waitcnt vmcnt(4)");   // (t+1).A0,B0 done
    __builtin_amdgcn_s_barrier();
  }

  // epilogue. C/D layout (m89/m91): col = lane&15, row = (lane>>4)*4 + reg.
  // strided wave tiling: row = m0+wr*16+mi*32+..., col = n0+wc*16+ni*64+fr
  const int col0 = n0 + wc * 16 + fr;
  const int row0 = m0 + wr * 16 + (lane >> 4) * 4;
#pragma unroll
  for (int ni = 0; ni < 4; ++ni) {
    const int col = col0 + ni * 64;
    const float bv = bias[col];
#pragma unroll
    for (int mi = 0; mi < 8; ++mi) {
#pragma unroll
      for (int r = 0; r < 4; ++r) {
        const int row = row0 + mi * 32 + r;
        float v = acc[mi][ni][r];
        if (FUSE_GELU) {
          v = gelu_tanh(v + bv);
          ((bf16*)Cout)[(size_t)row * N + col] = __float2bfloat16(v);
        } else {
          if (!isfinite(v)) v = 0.0f;   // nan_to_num BEFORE +b2
          ((float*)Cout)[(size_t)row * N + col] = v + bv;
        }
      }
    }
  }
}

extern "C" void kernel_launch(void* const* d_in, const int* in_sizes, int n_in,
                              void* d_out, int out_size, void* d_ws, size_t ws_size,
                              hipStream_t stream) {
  const float* x  = (const float*)d_in[0];
  const float* W1 = (const float*)d_in[1];
  const float* b1 = (const float*)d_in[2];
  const float* W2 = (const float*)d_in[3];
  const float* b2 = (const float*)d_in[4];
  float* out = (float*)d_out;

  // workspace layout (bf16): xb 32MB @0, h 128MB @32MB, w1t 128MB @160MB,
  // w2t 128MB @288MB (total 416 MB)
  char* ws = (char*)d_ws;
  bf16* xb  = (bf16*)(ws);
  bf16* h   = (bf16*)(ws + (size_t)32  * 1024 * 1024);
  bf16* w1t = (bf16*)(ws + (size_t)160 * 1024 * 1024);
  bf16* w2t = (bf16*)(ws + (size_t)288 * 1024 * 1024);

  cvt_f32_bf16<<<(TOKENS * DMODEL / 8) / 256, 256, 0, stream>>>(x, xb);
  transpose_cvt<<<dim3(DFF / 64, DMODEL / 64), 256, 0, stream>>>(W1, w1t, DMODEL, DFF);
  transpose_cvt<<<dim3(DMODEL / 64, DFF / 64), 256, 0, stream>>>(W2, w2t, DFF, DMODEL);

  // GEMM1: h = gelu(x @ W1 + b1)   [4096 x 16384] bf16
  gemm_bt<1><<<dim3((DFF / 256) * (TOKENS / 256)), 512, 0, stream>>>(
      xb, w1t, b1, h, TOKENS, DFF, DMODEL);

  // GEMM2: out = nan_guard(h @ W2) + b2   [4096 x 4096] f32
  gemm_bt<0><<<dim3((DMODEL / 256) * (TOKENS / 256)), 512, 0, stream>>>(
      h, w2t, b2, out, TOKENS, DMODEL, DFF);
}

// Round 8
// 1097.214 us; speedup vs baseline: 1.2504x; 1.0052x over previous
//
#include <hip/hip_runtime.h>
#include <hip/hip_bf16.h>

// FlashFFN: y = nan_to_num(gelu_tanh(x@W1 + b1) @ W2) + b2
// Round 10: balanced cross-phase ds_read pipeline on the r9 BK=64 ring.
// r9 readout: FETCH 590MB @1.26TB/s (memory solved), MfmaUtil 42%,
// 5484 cyc/K64 vs MFMA floor 2062 + LDS-read 2304 — LDS service is
// co-critical and the 12/8/4/0 read bursts + lgkm(0) serialize it against
// MFMA. Now: quadrant order Q1(A0B0) Q2(A1B0) Q3(A1B1) Q4(A0B1); reads
// spread 8/4/4/(8 post) one step ahead, gated by counted lgkm(8/4/4/-)
// so they fly UNDER the MFMA clusters. Staging order B-h0/A-h0/A-h1/B-h1
// publishes each half (own vmcnt(2) + barrier) exactly one phase before
// its first read. FIFO ledgers (lgkm & vmcnt) simulated incl. prologue
// and tail. Accumulation order per acc entry unchanged vs r9.

using bf16 = __hip_bfloat16;
typedef __attribute__((ext_vector_type(4))) float floatx4;
typedef __attribute__((ext_vector_type(8))) short shortx8;

#define TOKENS 4096   // B*S = 2*2048
#define DMODEL 4096
#define DFF    16384

__device__ __forceinline__ void gload_lds16(const void* g, void* l) {
  __builtin_amdgcn_global_load_lds(
      (const __attribute__((address_space(1))) unsigned int*)g,
      (__attribute__((address_space(3))) unsigned int*)l,
      16, 0, 0);
}

__device__ __forceinline__ unsigned lds_u32(const void* p) {
  return (unsigned)(unsigned long long)(const __attribute__((address_space(3))) char*)p;
}

__device__ __forceinline__ float gelu_tanh(float x) {
  // JAX default gelu (approximate=True, tanh form)
  float z = 0.7978845608028654f * (x + 0.044715f * x * x * x);
  float e = __expf(2.0f * z);   // inf -> t=1, 0 -> t=-1: both limits correct
  float t = 1.0f - 2.0f / (e + 1.0f);
  return 0.5f * x * (1.0f + t);
}

#define DSR(dst, addr, off) \
  asm volatile("ds_read_b128 %0, %1 offset:" #off : "=v"(dst) : "v"(addr))

// ---- pre-pass: f32 -> bf16 cast (layout preserved), 8 elems/thread ----
__global__ void cvt_f32_bf16(const float* __restrict__ in, bf16* __restrict__ out) {
  int i = (blockIdx.x * blockDim.x + threadIdx.x) * 8;
  float4 a = *(const float4*)(in + i);
  float4 b = *(const float4*)(in + i + 4);
  union { shortx8 v; bf16 h[8]; } r;
  r.h[0] = __float2bfloat16(a.x); r.h[1] = __float2bfloat16(a.y);
  r.h[2] = __float2bfloat16(a.z); r.h[3] = __float2bfloat16(a.w);
  r.h[4] = __float2bfloat16(b.x); r.h[5] = __float2bfloat16(b.y);
  r.h[6] = __float2bfloat16(b.z); r.h[7] = __float2bfloat16(b.w);
  *(shortx8*)(out + i) = r.v;
}

// ---- pre-pass: transpose + cast. in [R][C] f32 -> out [C][R] bf16 ----
__global__ void transpose_cvt(const float* __restrict__ in, bf16* __restrict__ out,
                              int R, int C) {
  __shared__ float tile[64][65];
  const int c0 = blockIdx.x * 64, r0 = blockIdx.y * 64;
  const int t = threadIdx.x;
#pragma unroll
  for (int p = 0; p < 4; ++p) {
    int r = p * 16 + (t >> 4);
    int c = (t & 15) * 4;
    float4 v = *(const float4*)(in + (size_t)(r0 + r) * C + c0 + c);
    tile[r][c] = v.x; tile[r][c + 1] = v.y;
    tile[r][c + 2] = v.z; tile[r][c + 3] = v.w;
  }
  __syncthreads();
#pragma unroll
  for (int p = 0; p < 2; ++p) {
    int c = p * 32 + (t >> 3);
    int rb = (t & 7) * 8;
    union { shortx8 v; bf16 h[8]; } u;
#pragma unroll
    for (int j = 0; j < 8; ++j) u.h[j] = __float2bfloat16(tile[rb + j][c]);
    *(shortx8*)(out + (size_t)(c0 + c) * R + r0 + rb) = u.v;
  }
}

// ---- BK=64 deep-pipelined GEMM with read-ahead: C = A @ Bt^T ----
template <int FUSE_GELU>
__launch_bounds__(512, 2)
__global__ void gemm_bt(const bf16* __restrict__ A, const bf16* __restrict__ Bt,
                        const float* __restrict__ bias, void* __restrict__ Cout,
                        int M, int N, int K) {
  // [dbuf][half][128][64] bf16 each
  __shared__ __align__(16) bf16 As[2 * 2 * 128 * 64];   // 64 KiB
  __shared__ __align__(16) bf16 Bs[2 * 2 * 128 * 64];   // 64 KiB

  const int tid = threadIdx.x;
  const int wave = tid >> 6;
  const int lane = tid & 63;

  // LLC-aware band mapping (r6, kept): nwg % 256 == 0 for both GEMMs.
  const int wg8  = blockIdx.x & 255;
  const int xcd  = wg8 & 7;
  const int slot = wg8 >> 3;
  const int m0 = (2 * xcd + (slot & 1)) * 256;
  const int n0 = ((blockIdx.x >> 8) * 16 + (slot >> 1)) * 256;

  const size_t Ks = (size_t)K;
  const int NT = K >> 6;   // # of BK=64 K-tiles (64 or 256 here)

  // ---- staging addressing (r9, proven): 8 contiguous rows x 128 B ----
  const int swz = (lane & 7) ^ ((lane >> 3) & 7);
  const bf16* agp = A  + (size_t)(m0 + wave * 8 + (lane >> 3)) * Ks + swz * 8;
  const bf16* bgp = Bt + (size_t)(n0 + wave * 8 + (lane >> 3)) * Ks + swz * 8;

  // ---- fragment-read addressing (r9, proven) ----
  const int wr = wave >> 2, wc = wave & 3;   // 2M x 4N
  const int fr = lane & 15;
  const int q  = lane >> 4;
  const unsigned As0 = lds_u32(As);
  const unsigned Bs0 = lds_u32(Bs);
  const unsigned aK0 = As0 + (unsigned)((wr * 16 + fr) * 128 +
                       (((fr >> 2) & 1) * 64) + ((q ^ (fr & 3)) * 16));
  const unsigned aK1 = aK0 ^ 64u;
  const unsigned bK0 = Bs0 + (unsigned)((wc * 16 + fr) * 128 +
                       (((fr >> 2) & 1) * 64) + ((q ^ (fr & 3)) * 16));
  const unsigned bK1 = bK0 ^ 64u;

  floatx4 acc[8][4] = {};
  shortx8 A0[2][4], A1[2][4], B0[2][2], B1[2][2];   // persistent fragments

  // ---- prologue: stage tile 0 (order A-h0,B-h0,A-h1,B-h1) ----
  {
    bf16* lA = As + wave * 512;
    bf16* lB = Bs + wave * 512;
    gload_lds16(agp,             lA);
    gload_lds16(agp +  64 * Ks,  lA + 4096);
    gload_lds16(bgp,             lB);
    gload_lds16(bgp +  64 * Ks,  lB + 4096);
    gload_lds16(agp + 128 * Ks,  lA + 8192);
    gload_lds16(agp + 192 * Ks,  lA + 12288);
    gload_lds16(bgp,             lB);       // placeholder replaced below
  }
  // NOTE: the placeholder above would corrupt; real prologue below.
  // (kept structure explicit: see corrected prologue)
  // -- corrected prologue staging (B-h1 last):
  {
    bf16* lB = Bs + wave * 512;
    gload_lds16(bgp + 128 * Ks,  lB + 8192);
    gload_lds16(bgp + 192 * Ks,  lB + 12288);
  }
  asm volatile("s_waitcnt vmcnt(3)");   // drain A-h0,B-h0,A-h1 (+dup B-h0)
  __builtin_amdgcn_s_barrier();
  // prologue reads: B0(0) then A0(0)  (FIFO order matches steady state)
  DSR(B0[0][0], bK0, 0); DSR(B0[0][1], bK0, 8192);
  DSR(B0[1][0], bK1, 0); DSR(B0[1][1], bK1, 8192);
  DSR(A0[0][0], aK0, 0);     DSR(A0[0][1], aK0, 4096);
  DSR(A0[0][2], aK0, 8192);  DSR(A0[0][3], aK0, 12288);
  DSR(A0[1][0], aK1, 0);     DSR(A0[1][1], aK1, 4096);
  DSR(A0[1][2], aK1, 8192);  DSR(A0[1][3], aK1, 12288);

  for (int t = 0; t < NT; ++t) {
    const unsigned dsel  = (unsigned)(t & 1) << 15;
    const unsigned dseln = (unsigned)((t + 1) & 1) << 15;
    const unsigned a0 = aK0 + dsel,  a1 = aK1 + dsel;
    const unsigned b0 = bK0 + dsel,  b1 = bK1 + dsel;
    const unsigned an0 = aK0 + dseln, an1 = aK1 + dseln;
    const unsigned bn0 = bK0 + dseln, bn1 = bK1 + dseln;
    const bool st = (t + 1 < NT);
    const bf16* gA = agp + (size_t)(t + 1) * 64;
    const bf16* gB = bgp + (size_t)(t + 1) * 64;
    bf16* lA = As + ((t + 1) & 1) * 16384 + wave * 512;
    bf16* lB = Bs + ((t + 1) & 1) * 16384 + wave * 512;

    // ===== phase 1: Q1 = A0·B0 -> acc[0..3][0..1]; pre-read A1(t);
    //        stage B-h0(t+1); publish B-h1(t) =====
    DSR(A1[0][0], a0, 16384); DSR(A1[0][1], a0, 20480);
    DSR(A1[0][2], a0, 24576); DSR(A1[0][3], a0, 28672);
    DSR(A1[1][0], a1, 16384); DSR(A1[1][1], a1, 20480);
    DSR(A1[1][2], a1, 24576); DSR(A1[1][3], a1, 28672);
    if (st) { gload_lds16(gB, lB); gload_lds16(gB + 64 * Ks, lB + 4096); }
    asm volatile("s_waitcnt lgkmcnt(8)");   // drain B0(t),A0(t); A1 flies
    __builtin_amdgcn_sched_barrier(0);
    __builtin_amdgcn_s_setprio(1);
#pragma unroll
    for (int f = 0; f < 4; ++f)
#pragma unroll
      for (int n = 0; n < 2; ++n) {
        acc[f][n] = __builtin_amdgcn_mfma_f32_16x16x32_bf16(A0[0][f], B0[0][n], acc[f][n], 0, 0, 0);
        acc[f][n] = __builtin_amdgcn_mfma_f32_16x16x32_bf16(A0[1][f], B0[1][n], acc[f][n], 0, 0, 0);
      }
    __builtin_amdgcn_s_setprio(0);
    __builtin_amdgcn_sched_barrier(0);
    if (st) asm volatile("s_waitcnt vmcnt(2)");   // B-h1(t) done
    else    asm volatile("s_waitcnt vmcnt(0)");
    __builtin_amdgcn_s_barrier();

    // ===== phase 2: Q2 = A1·B0 -> acc[4..7][0..1]; pre-read B1(t);
    //        stage A-h0(t+1); publish B-h0(t+1) =====
    DSR(B1[0][0], b0, 16384); DSR(B1[0][1], b0, 24576);
    DSR(B1[1][0], b1, 16384); DSR(B1[1][1], b1, 24576);
    if (st) { gload_lds16(gA, lA); gload_lds16(gA + 64 * Ks, lA + 4096); }
    asm volatile("s_waitcnt lgkmcnt(4)");   // drain A1(t); B1 flies
    __builtin_amdgcn_sched_barrier(0);
    __builtin_amdgcn_s_setprio(1);
#pragma unroll
    for (int f = 0; f < 4; ++f)
#pragma unroll
      for (int n = 0; n < 2; ++n) {
        acc[4 + f][n] = __builtin_amdgcn_mfma_f32_16x16x32_bf16(A1[0][f], B0[0][n], acc[4 + f][n], 0, 0, 0);
        acc[4 + f][n] = __builtin_amdgcn_mfma_f32_16x16x32_bf16(A1[1][f], B0[1][n], acc[4 + f][n], 0, 0, 0);
      }
    __builtin_amdgcn_s_setprio(0);
    __builtin_amdgcn_sched_barrier(0);
    if (st) asm volatile("s_waitcnt vmcnt(2)");   // B-h0(t+1) done
    __builtin_amdgcn_s_barrier();

    // ===== phase 3: Q3 = A1·B1 -> acc[4..7][2..3]; pre-read B0(t+1);
    //        stage A-h1(t+1); publish A-h0(t+1) =====
    if (st) {
      DSR(B0[0][0], bn0, 0); DSR(B0[0][1], bn0, 8192);
      DSR(B0[1][0], bn1, 0); DSR(B0[1][1], bn1, 8192);
      gload_lds16(gA + 128 * Ks, lA + 8192);
      gload_lds16(gA + 192 * Ks, lA + 12288);
      asm volatile("s_waitcnt lgkmcnt(4)");   // drain B1(t); B0n flies
    } else {
      asm volatile("s_waitcnt lgkmcnt(0)");   // drain B1(t)
    }
    __builtin_amdgcn_sched_barrier(0);
    __builtin_amdgcn_s_setprio(1);
#pragma unroll
    for (int f = 0; f < 4; ++f)
#pragma unroll
      for (int n = 0; n < 2; ++n) {
        acc[4 + f][2 + n] = __builtin_amdgcn_mfma_f32_16x16x32_bf16(A1[0][f], B1[0][n], acc[4 + f][2 + n], 0, 0, 0);
        acc[4 + f][2 + n] = __builtin_amdgcn_mfma_f32_16x16x32_bf16(A1[1][f], B1[1][n], acc[4 + f][2 + n], 0, 0, 0);
      }
    __builtin_amdgcn_s_setprio(0);
    __builtin_amdgcn_sched_barrier(0);
    if (st) asm volatile("s_waitcnt vmcnt(2)");   // A-h0(t+1) done
    __builtin_amdgcn_s_barrier();

    // ===== phase 4: Q4 = A0·B1 -> acc[0..3][2..3]; stage B-h1(t+1);
    //        post-read A0(t+1); publish A-h1(t+1) =====
    if (st) { gload_lds16(gB + 128 * Ks, lB + 8192); gload_lds16(gB + 192 * Ks, lB + 12288); }
    __builtin_amdgcn_s_setprio(1);
#pragma unroll
    for (int f = 0; f < 4; ++f)
#pragma unroll
      for (int n = 0; n < 2; ++n) {
        acc[f][2 + n] = __builtin_amdgcn_mfma_f32_16x16x32_bf16(A0[0][f], B1[0][n], acc[f][2 + n], 0, 0, 0);
        acc[f][2 + n] = __builtin_amdgcn_mfma_f32_16x16x32_bf16(A0[1][f], B1[1][n], acc[f][2 + n], 0, 0, 0);
      }
    __builtin_amdgcn_s_setprio(0);
    __builtin_amdgcn_sched_barrier(0);
    if (st) {   // post-cluster read-ahead: A0(t+1); drains at ph1's lgkm(8)
      DSR(A0[0][0], an0, 0);     DSR(A0[0][1], an0, 4096);
      DSR(A0[0][2], an0, 8192);  DSR(A0[0][3], an0, 12288);
      DSR(A0[1][0], an1, 0);     DSR(A0[1][1], an1, 4096);
      DSR(A0[1][2], an1, 8192);  DSR(A0[1][3], an1, 12288);
      asm volatile("s_waitcnt vmcnt(2)");   // A-h1(t+1) done
    }
    __builtin_amdgcn_s_barrier();
  }

  // epilogue. C/D layout (m89/m91): col = lane&15, row = (lane>>4)*4 + reg.
  // strided wave tiling: row = m0+wr*16+mi*32+..., col = n0+wc*16+ni*64+fr
  const int col0 = n0 + wc * 16 + fr;
  const int row0 = m0 + wr * 16 + (lane >> 4) * 4;
#pragma unroll
  for (int ni = 0; ni < 4; ++ni) {
    const int col = col0 + ni * 64;
    const float bv = bias[col];
#pragma unroll
    for (int mi = 0; mi < 8; ++mi) {
#pragma unroll
      for (int r = 0; r < 4; ++r) {
        const int row = row0 + mi * 32 + r;
        float v = acc[mi][ni][r];
        if (FUSE_GELU) {
          v = gelu_tanh(v + bv);
          ((bf16*)Cout)[(size_t)row * N + col] = __float2bfloat16(v);
        } else {
          if (!isfinite(v)) v = 0.0f;   // nan_to_num BEFORE +b2
          ((float*)Cout)[(size_t)row * N + col] = v + bv;
        }
      }
    }
  }
}

extern "C" void kernel_launch(void* const* d_in, const int* in_sizes, int n_in,
                              void* d_out, int out_size, void* d_ws, size_t ws_size,
                              hipStream_t stream) {
  const float* x  = (const float*)d_in[0];
  const float* W1 = (const float*)d_in[1];
  const float* b1 = (const float*)d_in[2];
  const float* W2 = (const float*)d_in[3];
  const float* b2 = (const float*)d_in[4];
  float* out = (float*)d_out;

  // workspace layout (bf16): xb 32MB @0, h 128MB @32MB, w1t 128MB @160MB,
  // w2t 128MB @288MB (total 416 MB)
  char* ws = (char*)d_ws;
  bf16* xb  = (bf16*)(ws);
  bf16* h   = (bf16*)(ws + (size_t)32  * 1024 * 1024);
  bf16* w1t = (bf16*)(ws + (size_t)160 * 1024 * 1024);
  bf16* w2t = (bf16*)(ws + (size_t)288 * 1024 * 1024);

  cvt_f32_bf16<<<(TOKENS * DMODEL / 8) / 256, 256, 0, stream>>>(x, xb);
  transpose_cvt<<<dim3(DFF / 64, DMODEL / 64), 256, 0, stream>>>(W1, w1t, DMODEL, DFF);
  transpose_cvt<<<dim3(DMODEL / 64, DFF / 64), 256, 0, stream>>>(W2, w2t, DFF, DMODEL);

  // GEMM1: h = gelu(x @ W1 + b1)   [4096 x 16384] bf16
  gemm_bt<1><<<dim3((DFF / 256) * (TOKENS / 256)), 512, 0, stream>>>(
      xb, w1t, b1, h, TOKENS, DFF, DMODEL);

  // GEMM2: out = nan_guard(h @ W2) + b2   [4096 x 4096] f32
  gemm_bt<0><<<dim3((DMODEL / 256) * (TOKENS / 256)), 512, 0, stream>>>(
      h, w2t, b2, out, TOKENS, DMODEL, DFF);
}